// Round 6
// baseline (144.151 us; speedup 1.0000x reference)
//
#include <hip/hip_runtime.h>
#include <cstdint>

#define E_DIM   1024
#define DH      32
#define M_FEAT  256
#define BT      16384

typedef __attribute__((ext_vector_type(8))) short bf16x8;
typedef __attribute__((ext_vector_type(4))) float f32x4;

// ws layout (shorts): proj W in MFMA-fragment order, flat = (nt*32 + sub)*512 + lane*8
#define WP_H_OFF 0
#define WP_L_OFF 65536

// ---- cheap 2-term bf16 split: h = trunc16(f), l = trunc16(f - h) ----
__device__ __forceinline__ unsigned perm_hi2(unsigned lo_src, unsigned hi_src) {
    // result = (hi16 of lo_src) | (hi16 of hi_src) << 16
#if __has_builtin(__builtin_amdgcn_perm)
    return __builtin_amdgcn_perm(hi_src, lo_src, 0x07060302u);
#else
    return (lo_src >> 16) | (hi_src & 0xFFFF0000u);
#endif
}

__device__ __forceinline__ void split2(float f0, float f1, unsigned& ph, unsigned& pl) {
    unsigned u0 = __builtin_bit_cast(unsigned, f0);
    unsigned u1 = __builtin_bit_cast(unsigned, f1);
    ph = perm_hi2(u0, u1);
    float d0 = f0 - __builtin_bit_cast(float, u0 & 0xFFFF0000u);
    float d1 = f1 - __builtin_bit_cast(float, u1 & 0xFFFF0000u);
    pl = perm_hi2(__builtin_bit_cast(unsigned, d0), __builtin_bit_cast(unsigned, d1));
}

__device__ __forceinline__ void split8(const float4& a, const float4& b,
                                       uint4& uh, uint4& ul) {
    split2(a.x, a.y, uh.x, ul.x);
    split2(a.z, a.w, uh.y, ul.y);
    split2(b.x, b.y, uh.z, ul.z);
    split2(b.z, b.w, uh.w, ul.w);
}

// ---------- prep v2: one B-fragment per thread; gathered reads (L2-hot W), coalesced b128 stores ----------
// fragment flat id = (nt*32 + sub)*64 + lane; element = Wcat[k = sub*32 + (lane>>4)*8 + j][n = nt*16 + (lane&15)]
__global__ __launch_bounds__(256) void k_prep(
    const float* __restrict__ Wq, const float* __restrict__ Wk,
    short* __restrict__ ws)
{
    const int idx  = blockIdx.x * 256 + threadIdx.x;   // 0..8191
    const int lane = idx & 63;
    const int sub  = (idx >> 6) & 31;
    const int nt   = idx >> 11;
    const int n    = nt * 16 + (lane & 15);
    const int kb   = sub * 32 + (lane >> 4) * 8;
    const float* __restrict__ src = (n < 32) ? (Wq + n) : (Wk + n - 32);
    float f[8];
#pragma unroll
    for (int j = 0; j < 8; ++j) f[j] = src[(size_t)(kb + j) * DH];
    uint4 uh, ul;
    split2(f[0], f[1], uh.x, ul.x);
    split2(f[2], f[3], uh.y, ul.y);
    split2(f[4], f[5], uh.z, ul.z);
    split2(f[6], f[7], uh.w, ul.w);
    *(uint4*)(ws + WP_H_OFF + (size_t)idx * 8) = uh;   // coalesced 16B stores
    *(uint4*)(ws + WP_L_OFF + (size_t)idx * 8) = ul;
}

// ---------- fused main: barrier-free K-loop, in-register A-fragments, no x LDS ----------
#define TB 16
#define QS 68    // qk row stride in floats
#define ZS 40    // z row stride in shorts

__global__ __launch_bounds__(256, 4) void k_main(
    const float* __restrict__ x, const float* __restrict__ bq,
    const float* __restrict__ bk, const short* __restrict__ ws,
    const float* __restrict__ w, float* __restrict__ out)
{
    __shared__ __align__(16) float qk_f[TB * QS];
    __shared__ __align__(16) short zh_s[TB * ZS];
    __shared__ __align__(16) short zl_s[TB * ZS];
    __shared__ float lnA_f[TB];

    const int tid  = threadIdx.x;
    const int lane = tid & 63;
    const int wv   = __builtin_amdgcn_readfirstlane(tid >> 6);  // 0..3
    const int ln15 = lane & 15;
    const int g    = lane >> 4;                                  // 0..3
    const long t0  = (long)blockIdx.x * TB;

    const int nrow = wv * 16 + ln15;   // proj output column 0..63
    const float bias = (nrow < 32) ? bq[nrow] : bk[nrow - 32];

    // -------- Phase 1: C[16 tok][64] = x @ [Wq|Wk], 3-pass split MFMA, NO barriers --------
    // A-frag for 32-k subchunk n: x[t0+ln15][n*32 + g*8 .. +8]  (32 B contiguous per lane)
    const float* xb  = x + (t0 + ln15) * (size_t)E_DIM + g * 8;
    const short* wsh = ws + WP_H_OFF + (size_t)(wv * 32) * 512 + lane * 8;
    const short* wsl = ws + WP_L_OFF + (size_t)(wv * 32) * 512 + lane * 8;

    f32x4 acc[2] = {{0.f,0.f,0.f,0.f}, {0.f,0.f,0.f,0.f}};
    float4 fxa[2], fxb[2];
    bf16x8 bh[2], bl[2];

#pragma unroll
    for (int n = 0; n < 2; ++n) {      // prologue: slots 0,1 in flight
        fxa[n] = *(const float4*)(xb + n * 32);
        fxb[n] = *(const float4*)(xb + n * 32 + 4);
        bh[n]  = *(const bf16x8*)(wsh + (size_t)n * 512);
        bl[n]  = *(const bf16x8*)(wsl + (size_t)n * 512);
    }

#pragma unroll
    for (int n = 0; n < 32; ++n) {     // 32 subchunks of 32-k; depth-2 register pipeline
        const int s = n & 1;
        uint4 uh, ul;
        split8(fxa[s], fxb[s], uh, ul);
        bf16x8 ah = __builtin_bit_cast(bf16x8, uh);
        bf16x8 al = __builtin_bit_cast(bf16x8, ul);
        acc[s] = __builtin_amdgcn_mfma_f32_16x16x32_bf16(ah, bh[s], acc[s], 0, 0, 0);
        acc[s] = __builtin_amdgcn_mfma_f32_16x16x32_bf16(ah, bl[s], acc[s], 0, 0, 0);
        acc[s] = __builtin_amdgcn_mfma_f32_16x16x32_bf16(al, bh[s], acc[s], 0, 0, 0);
        if (n < 30) {                  // refill slot for subchunk n+2
            fxa[s] = *(const float4*)(xb + (n + 2) * 32);
            fxb[s] = *(const float4*)(xb + (n + 2) * 32 + 4);
            bh[s]  = *(const bf16x8*)(wsh + (size_t)(n + 2) * 512);
            bl[s]  = *(const bf16x8*)(wsl + (size_t)(n + 2) * 512);
        }
    }

    f32x4 accv;
#pragma unroll
    for (int r = 0; r < 4; ++r) accv[r] = acc[0][r] + acc[1][r] + bias;

    // issue feature-w fp32 fragment loads now; barrier phases below cover their latency
    float4 wfa[4], wfb[4];
#pragma unroll
    for (int i = 0; i < 4; ++i) {
        const int nf = (wv * 4 + i) * 16 + ln15;    // feature 0..255
        wfa[i] = *(const float4*)(w + (size_t)nf * DH + g * 8);
        wfb[i] = *(const float4*)(w + (size_t)nf * DH + g * 8 + 4);
    }

    // -------- Phase 2: C/D layout row(tok)=g*4+r, col=nrow -> qk LDS --------
#pragma unroll
    for (int r = 0; r < 4; ++r)
        qk_f[(g * 4 + r) * QS + nrow] = accv[r];
    __syncthreads();

    // -------- Phase 3: z = q+k (split), lnA = -0.5(|q|^2+|k|^2) --------
    if (tid < 128) {
        const int tok = tid >> 3, grp = tid & 7;
        float4 qv = *(const float4*)&qk_f[tok * QS + grp * 4];
        float4 kv = *(const float4*)&qk_f[tok * QS + 32 + grp * 4];
        float z0 = qv.x + kv.x, z1 = qv.y + kv.y, z2 = qv.z + kv.z, z3 = qv.w + kv.w;
        float p = qv.x*qv.x + qv.y*qv.y + qv.z*qv.z + qv.w*qv.w
                + kv.x*kv.x + kv.y*kv.y + kv.z*kv.z + kv.w*kv.w;
        uint2 ph, pl;
        split2(z0, z1, ph.x, pl.x);
        split2(z2, z3, ph.y, pl.y);
        *(uint2*)&zh_s[tok * ZS + grp * 4] = ph;
        *(uint2*)&zl_s[tok * ZS + grp * 4] = pl;
        p += __shfl_xor(p, 1);
        p += __shfl_xor(p, 2);
        p += __shfl_xor(p, 4);
        if (grp == 0) lnA_f[tok] = -0.5f * p;
    }
    __syncthreads();

    // -------- Phase 4: S[16 tok][256] = z @ w^T (3-pass split); wave wv: features wv*64.. --------
    f32x4 facc[4];
#pragma unroll
    for (int i = 0; i < 4; ++i) facc[i] = (f32x4){0.f,0.f,0.f,0.f};

    bf16x8 a_h = *(const bf16x8*)&zh_s[ln15 * ZS + g * 8];
    bf16x8 a_l = *(const bf16x8*)&zl_s[ln15 * ZS + g * 8];
#pragma unroll
    for (int i = 0; i < 4; ++i) {
        uint4 uh, ul;
        split8(wfa[i], wfb[i], uh, ul);
        bf16x8 wh = __builtin_bit_cast(bf16x8, uh);
        bf16x8 wl = __builtin_bit_cast(bf16x8, ul);
        facc[i] = __builtin_amdgcn_mfma_f32_16x16x32_bf16(a_h, wh, facc[i], 0, 0, 0);
        facc[i] = __builtin_amdgcn_mfma_f32_16x16x32_bf16(a_h, wl, facc[i], 0, 0, 0);
        facc[i] = __builtin_amdgcn_mfma_f32_16x16x32_bf16(a_l, wh, facc[i], 0, 0, 0);
    }

    // -------- Phase 5: R = 0.5*(exp(lnA+s)+exp(lnA-s)) --------
    float lnAv[4];
#pragma unroll
    for (int r = 0; r < 4; ++r) lnAv[r] = lnA_f[g * 4 + r];

#pragma unroll
    for (int i = 0; i < 4; ++i) {
        const int n = (wv * 4 + i) * 16 + ln15;
#pragma unroll
        for (int r = 0; r < 4; ++r) {
            float s = facc[i][r];
            float R = 0.5f * (__expf(lnAv[r] + s) + __expf(lnAv[r] - s));
            out[(t0 + g * 4 + r) * M_FEAT + n] = R;
        }
    }
}

extern "C" void kernel_launch(void* const* d_in, const int* in_sizes, int n_in,
                              void* d_out, int out_size, void* d_ws, size_t ws_size,
                              hipStream_t stream) {
    const float* x  = (const float*)d_in[0];
    const float* Wq = (const float*)d_in[1];
    const float* bq = (const float*)d_in[2];
    const float* Wk = (const float*)d_in[3];
    const float* bk = (const float*)d_in[4];
    // d_in[5], d_in[6] = Wv, bv: dead in the reference
    const float* w  = (const float*)d_in[7];
    float* out = (float*)d_out;
    short* ws  = (short*)d_ws;   // 256 KB used

    k_prep<<<dim3(32), dim3(256), 0, stream>>>(Wq, Wk, ws);
    k_main<<<dim3(BT / TB), dim3(256), 0, stream>>>(x, bq, bk, ws, w, out);
}

// Round 7
// 127.102 us; speedup vs baseline: 1.1341x; 1.1341x over previous
//
#include <hip/hip_runtime.h>
#include <cstdint>

#define E_DIM   1024
#define DH      32
#define M_FEAT  256
#define BT      16384

typedef __attribute__((ext_vector_type(8))) short bf16x8;
typedef __attribute__((ext_vector_type(4))) float f32x4;

// ws layout (shorts): proj W in MFMA-fragment order, flat = (nt*32 + sub)*512 + lane*8
#define WP_H_OFF 0
#define WP_L_OFF 65536

// ---- cheap 2-term bf16 split: h = trunc16(f), l = trunc16(f - h) ----
__device__ __forceinline__ unsigned perm_hi2(unsigned lo_src, unsigned hi_src) {
    // result = (hi16 of lo_src) | (hi16 of hi_src) << 16
#if __has_builtin(__builtin_amdgcn_perm)
    return __builtin_amdgcn_perm(hi_src, lo_src, 0x07060302u);
#else
    return (lo_src >> 16) | (hi_src & 0xFFFF0000u);
#endif
}

__device__ __forceinline__ void split2(float f0, float f1, unsigned& ph, unsigned& pl) {
    unsigned u0 = __builtin_bit_cast(unsigned, f0);
    unsigned u1 = __builtin_bit_cast(unsigned, f1);
    ph = perm_hi2(u0, u1);
    float d0 = f0 - __builtin_bit_cast(float, u0 & 0xFFFF0000u);
    float d1 = f1 - __builtin_bit_cast(float, u1 & 0xFFFF0000u);
    pl = perm_hi2(__builtin_bit_cast(unsigned, d0), __builtin_bit_cast(unsigned, d1));
}

__device__ __forceinline__ void split8(const float4& a, const float4& b,
                                       uint4& uh, uint4& ul) {
    split2(a.x, a.y, uh.x, ul.x);
    split2(a.z, a.w, uh.y, ul.y);
    split2(b.x, b.y, uh.z, ul.z);
    split2(b.z, b.w, uh.w, ul.w);
}

// ---------- prep: coalesced LDS-transpose split of [Wq|Wk] into fragment order ----------
__global__ __launch_bounds__(256) void k_prep(
    const float* __restrict__ Wq, const float* __restrict__ Wk,
    short* __restrict__ ws)
{
    __shared__ float wlds[128 * 36];   // [k 0..127][n 0..31], stride 36 floats
    const int b = blockIdx.x, tid = threadIdx.x;
    const float* __restrict__ src = (b < 8) ? Wq : Wk;
    const int k0 = (b & 7) * 128;
    const int nbase = (b < 8) ? 0 : 32;
#pragma unroll
    for (int it = 0; it < 4; ++it) {               // coalesced read 128x32 floats
        int f = it * 256 + tid;                    // float4 index
        int k = f >> 3, c4 = f & 7;
        float4 v = *(const float4*)(src + (size_t)(k0 + k) * DH + c4 * 4);
        *(float4*)&wlds[k * 36 + c4 * 4] = v;
    }
    __syncthreads();
    const int n = tid >> 3, kq = tid & 7;
    const int n_g = nbase + n;
    const int nt = n_g >> 4, ln = n_g & 15;
#pragma unroll
    for (int rep = 0; rep < 4; ++rep) {
        int kk = rep * 8 + kq;                     // k-quad within this 128-slab
        int k_g = k0 + kk * 4;
        float f0 = wlds[(kk * 4 + 0) * 36 + n];
        float f1 = wlds[(kk * 4 + 1) * 36 + n];
        float f2 = wlds[(kk * 4 + 2) * 36 + n];
        float f3 = wlds[(kk * 4 + 3) * 36 + n];
        uint2 ph, pl;
        split2(f0, f1, ph.x, pl.x);
        split2(f2, f3, ph.y, pl.y);
        int sub = k_g >> 5;                        // global 32-k subchunk 0..31
        int g = (k_g >> 3) & 3, j0 = k_g & 7;
        int lane = g * 16 + ln;
        size_t flat = ((size_t)(nt * 32 + sub)) * 512 + lane * 8 + j0;
        *(uint2*)(ws + WP_H_OFF + flat) = ph;
        *(uint2*)(ws + WP_L_OFF + flat) = pl;
    }
}

// ---------- fused main: 16 tok/block, BK=128 pairs, LDS dbuf + DISTANCE-2 x reg pipeline ----------
#define TB 16
#define XS2 136  // x LDS row stride in shorts (128 data + 8 pad) = 272 B
#define QS 68    // qk row stride in floats
#define ZS 40    // z row stride in shorts

__global__ __launch_bounds__(256, 4) void k_main(
    const float* __restrict__ x, const float* __restrict__ bq,
    const float* __restrict__ bk, const short* __restrict__ ws,
    const float* __restrict__ w, float* __restrict__ out)
{
    __shared__ __align__(16) short xh_s[2][TB * XS2];
    __shared__ __align__(16) short xl_s[2][TB * XS2];
    __shared__ __align__(16) float qk_f[TB * QS];
    __shared__ __align__(16) short zh_s[TB * ZS];
    __shared__ __align__(16) short zl_s[TB * ZS];
    __shared__ float lnA_f[TB];

    const int tid  = threadIdx.x;
    const int lane = tid & 63;
    const int wv   = __builtin_amdgcn_readfirstlane(tid >> 6);  // 0..3
    const int ln15 = lane & 15;
    const int g    = lane >> 4;                                  // 0..3
    const long t0  = (long)blockIdx.x * TB;

    const int nrow = wv * 16 + ln15;   // proj output column 0..63
    const float bias = (nrow < 32) ? bq[nrow] : bk[nrow - 32];   // preload early

    // -------- Phase 1: C[16 tok][64] = x @ [Wq|Wk] (3-pass split bf16 MFMA) --------
    const int kq = tid & 15;          // 8-k group 0..15 within 128-wide pair
    const int mr = tid >> 4;          // token row 0..15

    f32x4 acc = {0.f, 0.f, 0.f, 0.f};

    const short* wpB_h = ws + WP_H_OFF + (size_t)(wv * 32) * 512 + lane * 8;
    const short* wpB_l = ws + WP_L_OFF + (size_t)(wv * 32) * 512 + lane * 8;
    const float* xrow  = x + (t0 + mr) * E_DIM + kq * 8;

    // x register pipeline, depth 2: set[0]/set[1], each holds one pair's 8 floats
    float4 sA[2], sB[2];
    bf16x8 bcur_h[4], bcur_l[4], bnxt_h[4], bnxt_l[4];

    // prologue: load pair 0 and pair 1; stage pair 0 -> LDS buf 0; preload B for pair 0
    sA[0] = *(const float4*)(xrow + 0);
    sB[0] = *(const float4*)(xrow + 4);
    sA[1] = *(const float4*)(xrow + 128);
    sB[1] = *(const float4*)(xrow + 132);
#pragma unroll
    for (int j = 0; j < 4; ++j) {
        bcur_h[j] = *(const bf16x8*)(wpB_h + (size_t)j * 512);
        bcur_l[j] = *(const bf16x8*)(wpB_l + (size_t)j * 512);
    }
    {
        uint4 uh, ul;
        split8(sA[0], sB[0], uh, ul);
        *(uint4*)&xh_s[0][mr * XS2 + kq * 8] = uh;
        *(uint4*)&xl_s[0][mr * XS2 + kq * 8] = ul;
    }

#pragma unroll
    for (int p = 0; p < 8; ++p) {
        __syncthreads();              // buf (p&1) fully staged; prior reads of it done
        // load pair p+2 into the set freed by pair p's store (set p&1)
        if (p < 6) {
            sA[p & 1] = *(const float4*)(xrow + (p + 2) * 128);
            sB[p & 1] = *(const float4*)(xrow + (p + 2) * 128 + 4);
        }
        // B fragments for pair p+1 (consumed next iteration)
        if (p < 7) {
#pragma unroll
            for (int j = 0; j < 4; ++j) {
                bnxt_h[j] = *(const bf16x8*)(wpB_h + (size_t)((p + 1) * 4 + j) * 512);
                bnxt_l[j] = *(const bf16x8*)(wpB_l + (size_t)((p + 1) * 4 + j) * 512);
            }
        }
        // compute pair p from LDS buf (p&1)
#pragma unroll
        for (int j = 0; j < 4; ++j) {
            bf16x8 ah = *(const bf16x8*)&xh_s[p & 1][ln15 * XS2 + j * 32 + g * 8];
            bf16x8 al = *(const bf16x8*)&xl_s[p & 1][ln15 * XS2 + j * 32 + g * 8];
            acc = __builtin_amdgcn_mfma_f32_16x16x32_bf16(ah, bcur_h[j], acc, 0, 0, 0);
            acc = __builtin_amdgcn_mfma_f32_16x16x32_bf16(ah, bcur_l[j], acc, 0, 0, 0);
            acc = __builtin_amdgcn_mfma_f32_16x16x32_bf16(al, bcur_h[j], acc, 0, 0, 0);
        }
        // store pair p+1 (loaded a full iteration ago) into the other LDS buffer
        if (p < 7) {
            uint4 uh, ul;
            split8(sA[(p + 1) & 1], sB[(p + 1) & 1], uh, ul);
            *(uint4*)&xh_s[(p + 1) & 1][mr * XS2 + kq * 8] = uh;
            *(uint4*)&xl_s[(p + 1) & 1][mr * XS2 + kq * 8] = ul;
#pragma unroll
            for (int j = 0; j < 4; ++j) {
                bcur_h[j] = bnxt_h[j];   // renamed away by full unroll
                bcur_l[j] = bnxt_l[j];
            }
        }
    }

    // issue feature-w fp32 fragment loads now; 2 barrier phases cover their latency
    float4 wfa[4], wfb[4];
#pragma unroll
    for (int i = 0; i < 4; ++i) {
        const int nf = (wv * 4 + i) * 16 + ln15;    // feature 0..255
        wfa[i] = *(const float4*)(w + (size_t)nf * DH + g * 8);
        wfb[i] = *(const float4*)(w + (size_t)nf * DH + g * 8 + 4);
    }

    // -------- Phase 2: +bias -> qk LDS (C/D layout: row(tok)=g*4+r, col=ln15) --------
#pragma unroll
    for (int r = 0; r < 4; ++r)
        qk_f[(g * 4 + r) * QS + nrow] = acc[r] + bias;
    __syncthreads();

    // -------- Phase 3: z = q+k (split), lnA = -0.5(|q|^2+|k|^2) --------
    if (tid < 128) {
        const int tok = tid >> 3, grp = tid & 7;
        float4 qv = *(const float4*)&qk_f[tok * QS + grp * 4];
        float4 kv = *(const float4*)&qk_f[tok * QS + 32 + grp * 4];
        float z0 = qv.x + kv.x, z1 = qv.y + kv.y, z2 = qv.z + kv.z, z3 = qv.w + kv.w;
        float p = qv.x*qv.x + qv.y*qv.y + qv.z*qv.z + qv.w*qv.w
                + kv.x*kv.x + kv.y*kv.y + kv.z*kv.z + kv.w*kv.w;
        uint2 ph, pl;
        split2(z0, z1, ph.x, pl.x);
        split2(z2, z3, ph.y, pl.y);
        *(uint2*)&zh_s[tok * ZS + grp * 4] = ph;
        *(uint2*)&zl_s[tok * ZS + grp * 4] = pl;
        p += __shfl_xor(p, 1);
        p += __shfl_xor(p, 2);
        p += __shfl_xor(p, 4);
        if (grp == 0) lnA_f[tok] = -0.5f * p;
    }
    __syncthreads();

    // -------- Phase 4: S[16 tok][256] = z @ w^T (3-pass split); wave wv: features wv*64.. --------
    f32x4 facc[4];
#pragma unroll
    for (int i = 0; i < 4; ++i) facc[i] = (f32x4){0.f,0.f,0.f,0.f};

    bf16x8 a_h = *(const bf16x8*)&zh_s[ln15 * ZS + g * 8];
    bf16x8 a_l = *(const bf16x8*)&zl_s[ln15 * ZS + g * 8];
#pragma unroll
    for (int i = 0; i < 4; ++i) {
        uint4 uh, ul;
        split8(wfa[i], wfb[i], uh, ul);
        bf16x8 wh = __builtin_bit_cast(bf16x8, uh);
        bf16x8 wl = __builtin_bit_cast(bf16x8, ul);
        facc[i] = __builtin_amdgcn_mfma_f32_16x16x32_bf16(a_h, wh, facc[i], 0, 0, 0);
        facc[i] = __builtin_amdgcn_mfma_f32_16x16x32_bf16(a_h, wl, facc[i], 0, 0, 0);
        facc[i] = __builtin_amdgcn_mfma_f32_16x16x32_bf16(a_l, wh, facc[i], 0, 0, 0);
    }

    // -------- Phase 5: R = 0.5*(exp(lnA+s)+exp(lnA-s)) --------
    float lnAv[4];
#pragma unroll
    for (int r = 0; r < 4; ++r) lnAv[r] = lnA_f[g * 4 + r];

#pragma unroll
    for (int i = 0; i < 4; ++i) {
        const int n = (wv * 4 + i) * 16 + ln15;
#pragma unroll
        for (int r = 0; r < 4; ++r) {
            float s = facc[i][r];
            float R = 0.5f * (__expf(lnAv[r] + s) + __expf(lnAv[r] - s));
            out[(t0 + g * 4 + r) * M_FEAT + n] = R;
        }
    }
}

extern "C" void kernel_launch(void* const* d_in, const int* in_sizes, int n_in,
                              void* d_out, int out_size, void* d_ws, size_t ws_size,
                              hipStream_t stream) {
    const float* x  = (const float*)d_in[0];
    const float* Wq = (const float*)d_in[1];
    const float* bq = (const float*)d_in[2];
    const float* Wk = (const float*)d_in[3];
    const float* bk = (const float*)d_in[4];
    // d_in[5], d_in[6] = Wv, bv: dead in the reference
    const float* w  = (const float*)d_in[7];
    float* out = (float*)d_out;
    short* ws  = (short*)d_ws;   // 256 KB used

    k_prep<<<dim3(16), dim3(256), 0, stream>>>(Wq, Wk, ws);
    k_main<<<dim3(BT / TB), dim3(256), 0, stream>>>(x, bq, bk, ws, w, out);
}

// Round 8
// 123.929 us; speedup vs baseline: 1.1632x; 1.0256x over previous
//
#include <hip/hip_runtime.h>
#include <cstdint>

#define E_DIM   1024
#define DH      32
#define M_FEAT  256
#define BT      16384

typedef __attribute__((ext_vector_type(8))) short bf16x8;
typedef __attribute__((ext_vector_type(4))) float f32x4;

// ws layout (shorts): proj W in MFMA-fragment order, flat = (nt*32 + sub)*512 + lane*8
#define WP_H_OFF 0
#define WP_L_OFF 65536

// ---- cheap 2-term bf16 split: h = trunc16(f), l = trunc16(f - h) ----
__device__ __forceinline__ unsigned perm_hi2(unsigned lo_src, unsigned hi_src) {
    // result = (hi16 of lo_src) | (hi16 of hi_src) << 16
#if __has_builtin(__builtin_amdgcn_perm)
    return __builtin_amdgcn_perm(hi_src, lo_src, 0x07060302u);
#else
    return (lo_src >> 16) | (hi_src & 0xFFFF0000u);
#endif
}

__device__ __forceinline__ void split2(float f0, float f1, unsigned& ph, unsigned& pl) {
    unsigned u0 = __builtin_bit_cast(unsigned, f0);
    unsigned u1 = __builtin_bit_cast(unsigned, f1);
    ph = perm_hi2(u0, u1);
    float d0 = f0 - __builtin_bit_cast(float, u0 & 0xFFFF0000u);
    float d1 = f1 - __builtin_bit_cast(float, u1 & 0xFFFF0000u);
    pl = perm_hi2(__builtin_bit_cast(unsigned, d0), __builtin_bit_cast(unsigned, d1));
}

__device__ __forceinline__ void split8(const float4& a, const float4& b,
                                       uint4& uh, uint4& ul) {
    split2(a.x, a.y, uh.x, ul.x);
    split2(a.z, a.w, uh.y, ul.y);
    split2(b.x, b.y, uh.z, ul.z);
    split2(b.z, b.w, uh.w, ul.w);
}

// ---------- prep: coalesced LDS-transpose split of [Wq|Wk] into fragment order ----------
__global__ __launch_bounds__(256) void k_prep(
    const float* __restrict__ Wq, const float* __restrict__ Wk,
    short* __restrict__ ws)
{
    __shared__ float wlds[128 * 36];   // [k 0..127][n 0..31], stride 36 floats
    const int b = blockIdx.x, tid = threadIdx.x;
    const float* __restrict__ src = (b < 8) ? Wq : Wk;
    const int k0 = (b & 7) * 128;
    const int nbase = (b < 8) ? 0 : 32;
#pragma unroll
    for (int it = 0; it < 4; ++it) {               // coalesced read 128x32 floats
        int f = it * 256 + tid;                    // float4 index
        int k = f >> 3, c4 = f & 7;
        float4 v = *(const float4*)(src + (size_t)(k0 + k) * DH + c4 * 4);
        *(float4*)&wlds[k * 36 + c4 * 4] = v;
    }
    __syncthreads();
    const int n = tid >> 3, kq = tid & 7;
    const int n_g = nbase + n;
    const int nt = n_g >> 4, ln = n_g & 15;
#pragma unroll
    for (int rep = 0; rep < 4; ++rep) {
        int kk = rep * 8 + kq;                     // k-quad within this 128-slab
        int k_g = k0 + kk * 4;
        float f0 = wlds[(kk * 4 + 0) * 36 + n];
        float f1 = wlds[(kk * 4 + 1) * 36 + n];
        float f2 = wlds[(kk * 4 + 2) * 36 + n];
        float f3 = wlds[(kk * 4 + 3) * 36 + n];
        uint2 ph, pl;
        split2(f0, f1, ph.x, pl.x);
        split2(f2, f3, ph.y, pl.y);
        int sub = k_g >> 5;                        // global 32-k subchunk 0..31
        int g = (k_g >> 3) & 3, j0 = k_g & 7;
        int lane = g * 16 + ln;
        size_t flat = ((size_t)(nt * 32 + sub)) * 512 + lane * 8 + j0;
        *(uint2*)(ws + WP_H_OFF + flat) = ph;
        *(uint2*)(ws + WP_L_OFF + flat) = pl;
    }
}

// ---------- fused main: ALL x loads issued upfront; barriers drain once; inline B ----------
#define TB 16
#define XS2 136  // x LDS row stride in shorts (128 data + 8 pad) = 272 B
#define QS 68    // qk row stride in floats
#define ZS 40    // z row stride in shorts

__global__ __launch_bounds__(256, 4) void k_main(
    const float* __restrict__ x, const float* __restrict__ bq,
    const float* __restrict__ bk, const short* __restrict__ ws,
    const float* __restrict__ w, float* __restrict__ out)
{
    __shared__ __align__(16) short xh_s[2][TB * XS2];
    __shared__ __align__(16) short xl_s[2][TB * XS2];
    __shared__ __align__(16) float qk_f[TB * QS];
    __shared__ __align__(16) short zh_s[TB * ZS];
    __shared__ __align__(16) short zl_s[TB * ZS];
    __shared__ float lnA_f[TB];

    const int tid  = threadIdx.x;
    const int lane = tid & 63;
    const int wv   = __builtin_amdgcn_readfirstlane(tid >> 6);  // 0..3
    const int ln15 = lane & 15;
    const int g    = lane >> 4;                                  // 0..3
    const long t0  = (long)blockIdx.x * TB;

    const int nrow = wv * 16 + ln15;   // proj output column 0..63
    const float bias = (nrow < 32) ? bq[nrow] : bk[nrow - 32];

    // -------- Phase 1: C[16 tok][64] = x @ [Wq|Wk] (3-pass split bf16 MFMA) --------
    const int kq = tid & 15;          // 8-k group 0..15 within 128-wide pair
    const int mr = tid >> 4;          // token row 0..15

    f32x4 acc = {0.f, 0.f, 0.f, 0.f};

    const short* wpB_h = ws + WP_H_OFF + (size_t)(wv * 32) * 512 + lane * 8;
    const short* wpB_l = ws + WP_L_OFF + (size_t)(wv * 32) * 512 + lane * 8;
    const float* xrow  = x + (t0 + mr) * E_DIM + kq * 8;

    // Issue the ENTIRE x-share now (16 dwordx4 = 64 B per thread per pair x 8 pairs).
    // Every __syncthreads drains vmcnt(0) anyway, so the only winning schedule is
    // max MLP upfront: pair-0's barrier pays one HBM-BW drain; later barriers ~free.
    float4 st[16];
#pragma unroll
    for (int p = 0; p < 8; ++p) {
        st[2 * p]     = *(const float4*)(xrow + p * 128);
        st[2 * p + 1] = *(const float4*)(xrow + p * 128 + 4);
    }
    {   // stage pair 0 -> LDS buf 0 (waits only on the first two loads; rest keep draining)
        uint4 uh, ul;
        split8(st[0], st[1], uh, ul);
        *(uint4*)&xh_s[0][mr * XS2 + kq * 8] = uh;
        *(uint4*)&xl_s[0][mr * XS2 + kq * 8] = ul;
    }

#pragma unroll
    for (int p = 0; p < 8; ++p) {
        __syncthreads();              // buf (p&1) staged; pair-0 iter: drains all x loads
        // B fragments for this pair, inline (L2-resident ws; latency TLP-hidden)
        bf16x8 bh[4], bl[4];
#pragma unroll
        for (int j = 0; j < 4; ++j) {
            bh[j] = *(const bf16x8*)(wpB_h + (size_t)(p * 4 + j) * 512);
            bl[j] = *(const bf16x8*)(wpB_l + (size_t)(p * 4 + j) * 512);
        }
#pragma unroll
        for (int j = 0; j < 4; ++j) {
            bf16x8 ah = *(const bf16x8*)&xh_s[p & 1][ln15 * XS2 + j * 32 + g * 8];
            bf16x8 al = *(const bf16x8*)&xl_s[p & 1][ln15 * XS2 + j * 32 + g * 8];
            acc = __builtin_amdgcn_mfma_f32_16x16x32_bf16(ah, bh[j], acc, 0, 0, 0);
            acc = __builtin_amdgcn_mfma_f32_16x16x32_bf16(ah, bl[j], acc, 0, 0, 0);
            acc = __builtin_amdgcn_mfma_f32_16x16x32_bf16(al, bh[j], acc, 0, 0, 0);
        }
        if (p < 7) {                  // stage pair p+1 from registers (already resident)
            uint4 uh, ul;
            split8(st[2 * p + 2], st[2 * p + 3], uh, ul);
            *(uint4*)&xh_s[(p + 1) & 1][mr * XS2 + kq * 8] = uh;
            *(uint4*)&xl_s[(p + 1) & 1][mr * XS2 + kq * 8] = ul;
        }
    }

    // issue feature-w fp32 fragment loads now; 2 barrier phases cover their latency
    float4 wfa[4], wfb[4];
#pragma unroll
    for (int i = 0; i < 4; ++i) {
        const int nf = (wv * 4 + i) * 16 + ln15;    // feature 0..255
        wfa[i] = *(const float4*)(w + (size_t)nf * DH + g * 8);
        wfb[i] = *(const float4*)(w + (size_t)nf * DH + g * 8 + 4);
    }

    // -------- Phase 2: +bias -> qk LDS (C/D layout: row(tok)=g*4+r, col=ln15) --------
#pragma unroll
    for (int r = 0; r < 4; ++r)
        qk_f[(g * 4 + r) * QS + nrow] = acc[r] + bias;
    __syncthreads();

    // -------- Phase 3: z = q+k (split), lnA = -0.5(|q|^2+|k|^2) --------
    if (tid < 128) {
        const int tok = tid >> 3, grp = tid & 7;
        float4 qv = *(const float4*)&qk_f[tok * QS + grp * 4];
        float4 kv = *(const float4*)&qk_f[tok * QS + 32 + grp * 4];
        float z0 = qv.x + kv.x, z1 = qv.y + kv.y, z2 = qv.z + kv.z, z3 = qv.w + kv.w;
        float p = qv.x*qv.x + qv.y*qv.y + qv.z*qv.z + qv.w*qv.w
                + kv.x*kv.x + kv.y*kv.y + kv.z*kv.z + kv.w*kv.w;
        uint2 ph, pl;
        split2(z0, z1, ph.x, pl.x);
        split2(z2, z3, ph.y, pl.y);
        *(uint2*)&zh_s[tok * ZS + grp * 4] = ph;
        *(uint2*)&zl_s[tok * ZS + grp * 4] = pl;
        p += __shfl_xor(p, 1);
        p += __shfl_xor(p, 2);
        p += __shfl_xor(p, 4);
        if (grp == 0) lnA_f[tok] = -0.5f * p;
    }
    __syncthreads();

    // -------- Phase 4: S[16 tok][256] = z @ w^T (3-pass split); wave wv: features wv*64.. --------
    f32x4 facc[4];
#pragma unroll
    for (int i = 0; i < 4; ++i) facc[i] = (f32x4){0.f,0.f,0.f,0.f};

    bf16x8 a_h = *(const bf16x8*)&zh_s[ln15 * ZS + g * 8];
    bf16x8 a_l = *(const bf16x8*)&zl_s[ln15 * ZS + g * 8];
#pragma unroll
    for (int i = 0; i < 4; ++i) {
        uint4 uh, ul;
        split8(wfa[i], wfb[i], uh, ul);
        bf16x8 wh = __builtin_bit_cast(bf16x8, uh);
        bf16x8 wl = __builtin_bit_cast(bf16x8, ul);
        facc[i] = __builtin_amdgcn_mfma_f32_16x16x32_bf16(a_h, wh, facc[i], 0, 0, 0);
        facc[i] = __builtin_amdgcn_mfma_f32_16x16x32_bf16(a_h, wl, facc[i], 0, 0, 0);
        facc[i] = __builtin_amdgcn_mfma_f32_16x16x32_bf16(a_l, wh, facc[i], 0, 0, 0);
    }

    // -------- Phase 5: R = 0.5*(exp(lnA+s)+exp(lnA-s)) --------
    float lnAv[4];
#pragma unroll
    for (int r = 0; r < 4; ++r) lnAv[r] = lnA_f[g * 4 + r];

#pragma unroll
    for (int i = 0; i < 4; ++i) {
        const int n = (wv * 4 + i) * 16 + ln15;
#pragma unroll
        for (int r = 0; r < 4; ++r) {
            float s = facc[i][r];
            float R = 0.5f * (__expf(lnAv[r] + s) + __expf(lnAv[r] - s));
            out[(t0 + g * 4 + r) * M_FEAT + n] = R;
        }
    }
}

extern "C" void kernel_launch(void* const* d_in, const int* in_sizes, int n_in,
                              void* d_out, int out_size, void* d_ws, size_t ws_size,
                              hipStream_t stream) {
    const float* x  = (const float*)d_in[0];
    const float* Wq = (const float*)d_in[1];
    const float* bq = (const float*)d_in[2];
    const float* Wk = (const float*)d_in[3];
    const float* bk = (const float*)d_in[4];
    // d_in[5], d_in[6] = Wv, bv: dead in the reference
    const float* w  = (const float*)d_in[7];
    float* out = (float*)d_out;
    short* ws  = (short*)d_ws;   // 256 KB used

    k_prep<<<dim3(16), dim3(256), 0, stream>>>(Wq, Wk, ws);
    k_main<<<dim3(BT / TB), dim3(256), 0, stream>>>(x, bq, bk, ws, w, out);
}

// Round 9
// 122.113 us; speedup vs baseline: 1.1805x; 1.0149x over previous
//
#include <hip/hip_runtime.h>
#include <cstdint>

#define E_DIM   1024
#define DH      32
#define M_FEAT  256
#define BT      16384

typedef __attribute__((ext_vector_type(8))) short bf16x8;
typedef __attribute__((ext_vector_type(4))) float f32x4;

// ws layout (shorts): proj W in MFMA-fragment order, flat = (nt*32 + sub)*512 + lane*8
#define WP_H_OFF 0
#define WP_L_OFF 65536

// ---- cheap 2-term bf16 split: h = trunc16(f), l = trunc16(f - h) ----
__device__ __forceinline__ unsigned perm_hi2(unsigned lo_src, unsigned hi_src) {
#if __has_builtin(__builtin_amdgcn_perm)
    return __builtin_amdgcn_perm(hi_src, lo_src, 0x07060302u);
#else
    return (lo_src >> 16) | (hi_src & 0xFFFF0000u);
#endif
}

__device__ __forceinline__ void split2(float f0, float f1, unsigned& ph, unsigned& pl) {
    unsigned u0 = __builtin_bit_cast(unsigned, f0);
    unsigned u1 = __builtin_bit_cast(unsigned, f1);
    ph = perm_hi2(u0, u1);
    float d0 = f0 - __builtin_bit_cast(float, u0 & 0xFFFF0000u);
    float d1 = f1 - __builtin_bit_cast(float, u1 & 0xFFFF0000u);
    pl = perm_hi2(__builtin_bit_cast(unsigned, d0), __builtin_bit_cast(unsigned, d1));
}

__device__ __forceinline__ void split8(const float4& a, const float4& b,
                                       uint4& uh, uint4& ul) {
    split2(a.x, a.y, uh.x, ul.x);
    split2(a.z, a.w, uh.y, ul.y);
    split2(b.x, b.y, uh.z, ul.z);
    split2(b.z, b.w, uh.w, ul.w);
}

// ---------- prep: 32 blocks, each a 64-k half-slab; LDS transpose -> fragment order ----------
__global__ __launch_bounds__(256) void k_prep(
    const float* __restrict__ Wq, const float* __restrict__ Wk,
    short* __restrict__ ws)
{
    __shared__ float wlds[64 * 36];    // [k 0..63][n 0..31], stride 36 floats
    const int b = blockIdx.x, tid = threadIdx.x;
    const float* __restrict__ src = (b < 16) ? Wq : Wk;
    const int k0 = (b & 15) * 64;
    const int nbase = (b < 16) ? 0 : 32;
#pragma unroll
    for (int it = 0; it < 2; ++it) {               // coalesced read 64x32 floats
        int f = it * 256 + tid;                    // float4 index
        int k = f >> 3, c4 = f & 7;
        float4 v = *(const float4*)(src + (size_t)(k0 + k) * DH + c4 * 4);
        *(float4*)&wlds[k * 36 + c4 * 4] = v;
    }
    __syncthreads();
    const int n = tid >> 3, kq = tid & 7;
    const int n_g = nbase + n;
    const int nt = n_g >> 4, ln = n_g & 15;
#pragma unroll
    for (int rep = 0; rep < 2; ++rep) {
        int kk = rep * 8 + kq;                     // k-quad within this 64-slab
        int k_g = k0 + kk * 4;
        float f0 = wlds[(kk * 4 + 0) * 36 + n];
        float f1 = wlds[(kk * 4 + 1) * 36 + n];
        float f2 = wlds[(kk * 4 + 2) * 36 + n];
        float f3 = wlds[(kk * 4 + 3) * 36 + n];
        uint2 ph, pl;
        split2(f0, f1, ph.x, pl.x);
        split2(f2, f3, ph.y, pl.y);
        int sub = k_g >> 5;                        // global 32-k subchunk 0..31
        int g = (k_g >> 3) & 3, j0 = k_g & 7;
        int lane = g * 16 + ln;
        size_t flat = ((size_t)(nt * 32 + sub)) * 512 + lane * 8 + j0;
        *(uint2*)(ws + WP_H_OFF + flat) = ph;
        *(uint2*)(ws + WP_L_OFF + flat) = pl;
    }
}

// ---------- fused main: TB=32 (2 m-tiles/wave) halves B L2 traffic; LDS dbuf; inline B ----------
#define TB 32
#define XS2 136  // x LDS row stride in shorts (128 data + 8 pad) = 272 B
#define QS 68    // qk row stride in floats
#define ZS 40    // z row stride in shorts

__global__ __launch_bounds__(256, 3) void k_main(
    const float* __restrict__ x, const float* __restrict__ bq,
    const float* __restrict__ bk, const short* __restrict__ ws,
    const float* __restrict__ w, float* __restrict__ out)
{
    __shared__ __align__(16) short xh_s[2][TB * XS2];
    __shared__ __align__(16) short xl_s[2][TB * XS2];
    __shared__ __align__(16) float qk_f[TB * QS];
    __shared__ __align__(16) short zh_s[TB * ZS];
    __shared__ __align__(16) short zl_s[TB * ZS];
    __shared__ float lnA_f[TB];

    const int tid  = threadIdx.x;
    const int lane = tid & 63;
    const int wv   = __builtin_amdgcn_readfirstlane(tid >> 6);  // 0..3
    const int ln15 = lane & 15;
    const int g    = lane >> 4;                                  // 0..3
    const long t0  = (long)blockIdx.x * TB;

    const int nrow = wv * 16 + ln15;   // proj output column 0..63
    const float bias = (nrow < 32) ? bq[nrow] : bk[nrow - 32];

    // -------- Phase 1: C[32 tok][64] = x @ [Wq|Wk] (3-pass split bf16 MFMA) --------
    const int kq = tid & 15;          // 8-k group 0..15 within 128-wide pair
    const int mr = tid >> 4;          // token row 0..15 (also handles mr+16)

    f32x4 acc0 = {0.f, 0.f, 0.f, 0.f};   // tokens 0..15
    f32x4 acc1 = {0.f, 0.f, 0.f, 0.f};   // tokens 16..31

    const short* wpB_h = ws + WP_H_OFF + (size_t)(wv * 32) * 512 + lane * 8;
    const short* wpB_l = ws + WP_L_OFF + (size_t)(wv * 32) * 512 + lane * 8;
    const float* xr0 = x + (t0 + mr) * (size_t)E_DIM + kq * 8;
    const float* xr1 = x + (t0 + mr + 16) * (size_t)E_DIM + kq * 8;

    // distance-1 x register prefetch (equivalent to upfront under barrier drain)
    float4 a0 = *(const float4*)(xr0 + 0), b0 = *(const float4*)(xr0 + 4);
    float4 a1 = *(const float4*)(xr1 + 0), b1 = *(const float4*)(xr1 + 4);
    {
        uint4 uh, ul;
        split8(a0, b0, uh, ul);
        *(uint4*)&xh_s[0][mr * XS2 + kq * 8] = uh;
        *(uint4*)&xl_s[0][mr * XS2 + kq * 8] = ul;
        split8(a1, b1, uh, ul);
        *(uint4*)&xh_s[0][(mr + 16) * XS2 + kq * 8] = uh;
        *(uint4*)&xl_s[0][(mr + 16) * XS2 + kq * 8] = ul;
    }

#pragma unroll
    for (int p = 0; p < 8; ++p) {
        __syncthreads();              // buf (p&1) fully staged; prior reads of it done
        if (p < 7) {                  // prefetch pair p+1
            a0 = *(const float4*)(xr0 + (p + 1) * 128);
            b0 = *(const float4*)(xr0 + (p + 1) * 128 + 4);
            a1 = *(const float4*)(xr1 + (p + 1) * 128);
            b1 = *(const float4*)(xr1 + (p + 1) * 128 + 4);
        }
        // B fragments for this pair, inline (L2-resident ws)
#pragma unroll
        for (int j = 0; j < 4; ++j) {
            bf16x8 bh = *(const bf16x8*)(wpB_h + (size_t)(p * 4 + j) * 512);
            bf16x8 bl = *(const bf16x8*)(wpB_l + (size_t)(p * 4 + j) * 512);
            bf16x8 ah0 = *(const bf16x8*)&xh_s[p & 1][ln15 * XS2 + j * 32 + g * 8];
            bf16x8 al0 = *(const bf16x8*)&xl_s[p & 1][ln15 * XS2 + j * 32 + g * 8];
            bf16x8 ah1 = *(const bf16x8*)&xh_s[p & 1][(ln15 + 16) * XS2 + j * 32 + g * 8];
            bf16x8 al1 = *(const bf16x8*)&xl_s[p & 1][(ln15 + 16) * XS2 + j * 32 + g * 8];
            acc0 = __builtin_amdgcn_mfma_f32_16x16x32_bf16(ah0, bh, acc0, 0, 0, 0);
            acc0 = __builtin_amdgcn_mfma_f32_16x16x32_bf16(ah0, bl, acc0, 0, 0, 0);
            acc0 = __builtin_amdgcn_mfma_f32_16x16x32_bf16(al0, bh, acc0, 0, 0, 0);
            acc1 = __builtin_amdgcn_mfma_f32_16x16x32_bf16(ah1, bh, acc1, 0, 0, 0);
            acc1 = __builtin_amdgcn_mfma_f32_16x16x32_bf16(ah1, bl, acc1, 0, 0, 0);
            acc1 = __builtin_amdgcn_mfma_f32_16x16x32_bf16(al1, bh, acc1, 0, 0, 0);
        }
        if (p < 7) {                  // stage pair p+1 into the other buffer
            uint4 uh, ul;
            split8(a0, b0, uh, ul);
            *(uint4*)&xh_s[(p + 1) & 1][mr * XS2 + kq * 8] = uh;
            *(uint4*)&xl_s[(p + 1) & 1][mr * XS2 + kq * 8] = ul;
            split8(a1, b1, uh, ul);
            *(uint4*)&xh_s[(p + 1) & 1][(mr + 16) * XS2 + kq * 8] = uh;
            *(uint4*)&xl_s[(p + 1) & 1][(mr + 16) * XS2 + kq * 8] = ul;
        }
    }

    // issue feature-w fp32 fragment loads; barrier phases below cover their latency
    float4 wfa[4], wfb[4];
#pragma unroll
    for (int i = 0; i < 4; ++i) {
        const int nf = (wv * 4 + i) * 16 + ln15;    // feature 0..255
        wfa[i] = *(const float4*)(w + (size_t)nf * DH + g * 8);
        wfb[i] = *(const float4*)(w + (size_t)nf * DH + g * 8 + 4);
    }

    // -------- Phase 2: +bias -> qk LDS (C/D layout: row(tok)=g*4+r, col=ln15) --------
#pragma unroll
    for (int r = 0; r < 4; ++r) {
        qk_f[(g * 4 + r) * QS + nrow]        = acc0[r] + bias;
        qk_f[(16 + g * 4 + r) * QS + nrow]   = acc1[r] + bias;
    }
    __syncthreads();

    // -------- Phase 3: z = q+k (split), lnA = -0.5(|q|^2+|k|^2); 32 tok x 8 grp --------
    {
        const int tok = tid >> 3, grp = tid & 7;
        float4 qv = *(const float4*)&qk_f[tok * QS + grp * 4];
        float4 kv = *(const float4*)&qk_f[tok * QS + 32 + grp * 4];
        float z0 = qv.x + kv.x, z1 = qv.y + kv.y, z2 = qv.z + kv.z, z3 = qv.w + kv.w;
        float p = qv.x*qv.x + qv.y*qv.y + qv.z*qv.z + qv.w*qv.w
                + kv.x*kv.x + kv.y*kv.y + kv.z*kv.z + kv.w*kv.w;
        uint2 ph, pl;
        split2(z0, z1, ph.x, pl.x);
        split2(z2, z3, ph.y, pl.y);
        *(uint2*)&zh_s[tok * ZS + grp * 4] = ph;
        *(uint2*)&zl_s[tok * ZS + grp * 4] = pl;
        p += __shfl_xor(p, 1);
        p += __shfl_xor(p, 2);
        p += __shfl_xor(p, 4);
        if (grp == 0) lnA_f[tok] = -0.5f * p;
    }
    __syncthreads();

    // -------- Phase 4: S[32 tok][256] = z @ w^T (3-pass split); wave wv: features wv*64.. --------
    f32x4 facc[4][2];
#pragma unroll
    for (int i = 0; i < 4; ++i)
#pragma unroll
        for (int mt = 0; mt < 2; ++mt) facc[i][mt] = (f32x4){0.f,0.f,0.f,0.f};

    bf16x8 a_h[2], a_l[2];
#pragma unroll
    for (int mt = 0; mt < 2; ++mt) {
        a_h[mt] = *(const bf16x8*)&zh_s[(mt * 16 + ln15) * ZS + g * 8];
        a_l[mt] = *(const bf16x8*)&zl_s[(mt * 16 + ln15) * ZS + g * 8];
    }
#pragma unroll
    for (int i = 0; i < 4; ++i) {
        uint4 uh, ul;
        split8(wfa[i], wfb[i], uh, ul);
        bf16x8 wh = __builtin_bit_cast(bf16x8, uh);
        bf16x8 wl = __builtin_bit_cast(bf16x8, ul);
#pragma unroll
        for (int mt = 0; mt < 2; ++mt) {
            facc[i][mt] = __builtin_amdgcn_mfma_f32_16x16x32_bf16(a_h[mt], wh, facc[i][mt], 0, 0, 0);
            facc[i][mt] = __builtin_amdgcn_mfma_f32_16x16x32_bf16(a_h[mt], wl, facc[i][mt], 0, 0, 0);
            facc[i][mt] = __builtin_amdgcn_mfma_f32_16x16x32_bf16(a_l[mt], wh, facc[i][mt], 0, 0, 0);
        }
    }

    // -------- Phase 5: R = 0.5*(exp(lnA+s)+exp(lnA-s)) --------
    float lnAv[2][4];
#pragma unroll
    for (int mt = 0; mt < 2; ++mt)
#pragma unroll
        for (int r = 0; r < 4; ++r) lnAv[mt][r] = lnA_f[mt * 16 + g * 4 + r];

#pragma unroll
    for (int i = 0; i < 4; ++i) {
        const int n = (wv * 4 + i) * 16 + ln15;
#pragma unroll
        for (int mt = 0; mt < 2; ++mt) {
#pragma unroll
            for (int r = 0; r < 4; ++r) {
                float s = facc[i][mt][r];
                float R = 0.5f * (__expf(lnAv[mt][r] + s) + __expf(lnAv[mt][r] - s));
                out[(t0 + mt * 16 + g * 4 + r) * M_FEAT + n] = R;
            }
        }
    }
}

extern "C" void kernel_launch(void* const* d_in, const int* in_sizes, int n_in,
                              void* d_out, int out_size, void* d_ws, size_t ws_size,
                              hipStream_t stream) {
    const float* x  = (const float*)d_in[0];
    const float* Wq = (const float*)d_in[1];
    const float* bq = (const float*)d_in[2];
    const float* Wk = (const float*)d_in[3];
    const float* bk = (const float*)d_in[4];
    // d_in[5], d_in[6] = Wv, bv: dead in the reference
    const float* w  = (const float*)d_in[7];
    float* out = (float*)d_out;
    short* ws  = (short*)d_ws;   // 256 KB used

    k_prep<<<dim3(32), dim3(256), 0, stream>>>(Wq, Wk, ws);
    k_main<<<dim3(BT / TB), dim3(256), 0, stream>>>(x, bq, bk, ws, w, out);
}